// Round 16
// baseline (784.069 us; speedup 1.0000x reference)
//
#include <hip/hip_runtime.h>
#include <math.h>

typedef unsigned short u16;
typedef unsigned int u32;
typedef __attribute__((ext_vector_type(8))) short bf16x8;
typedef __attribute__((ext_vector_type(4))) float f32x4;
typedef __attribute__((ext_vector_type(4))) u16 u16x4;

__device__ __forceinline__ u16 f2bf(float f) {
  u32 u = __builtin_bit_cast(u32, f);
  u32 r = (u + 0x7fffu + ((u >> 16) & 1u)) >> 16;
  return (u16)r;
}

// fast gelu: v*sigmoid(1.5957691*v*(1+0.044715*v^2)); |err|<3e-3 << 0.1175 thr
__device__ __forceinline__ float gelu_f(float v) {
  float u = 1.5957691216057308f * v * (1.0f + 0.044715f * v * v);
  return v / (1.0f + __expf(-u));
}

__device__ __forceinline__ void async16(const void* g, void* l) {
  __builtin_amdgcn_global_load_lds(
      (__attribute__((address_space(1))) void*)(unsigned long long)(const char*)g,
      (__attribute__((address_space(3))) void*)l, 16, 0, 0);
}

#define SCHED0 __builtin_amdgcn_sched_barrier(0)
#define BARRIER __builtin_amdgcn_s_barrier()

// ---------------------------------------------------------------------------
// LayerNorm row-block body (4 rows, 4 waves), f32 in -> bf16 out
// ---------------------------------------------------------------------------
__device__ __forceinline__ void ln_rows4(
    const float* __restrict__ in1, const float* __restrict__ g1, const float* __restrict__ b1,
    u16* __restrict__ out1, int rows1,
    const float* __restrict__ in2, const float* __restrict__ g2v, const float* __restrict__ b2v,
    u16* __restrict__ out2, int rowblk)
{
  const int w = threadIdx.x >> 6;
  const int lane = threadIdx.x & 63;
  const int row = rowblk * 4 + w;
  const float* in; const float* gg; const float* bb; u16* out;
  if (row < rows1) { in = in1 + (size_t)row * 768; gg = g1; bb = b1; out = out1 + (size_t)row * 768; }
  else { const int r2 = row - rows1; in = in2 + (size_t)r2 * 768; gg = g2v; bb = b2v; out = out2 + (size_t)r2 * 768; }

  float4 v0 = *(const float4*)&in[lane * 4];
  float4 v1 = *(const float4*)&in[lane * 4 + 256];
  float4 v2 = *(const float4*)&in[lane * 4 + 512];
  float s = v0.x + v0.y + v0.z + v0.w + v1.x + v1.y + v1.z + v1.w + v2.x + v2.y + v2.z + v2.w;
  float s2 = v0.x*v0.x + v0.y*v0.y + v0.z*v0.z + v0.w*v0.w
           + v1.x*v1.x + v1.y*v1.y + v1.z*v1.z + v1.w*v1.w
           + v2.x*v2.x + v2.y*v2.y + v2.z*v2.z + v2.w*v2.w;
#pragma unroll
  for (int m = 1; m <= 32; m <<= 1) { s += __shfl_xor(s, m); s2 += __shfl_xor(s2, m); }
  const float mean = s * (1.0f / 768.0f);
  const float var = s2 * (1.0f / 768.0f) - mean * mean;
  const float rs = rsqrtf(var + 1e-5f);

#define LNSTORE(V, OFFS) { \
    float4 gv = *(const float4*)&gg[lane * 4 + OFFS]; \
    float4 bv = *(const float4*)&bb[lane * 4 + OFFS]; \
    u16x4 o; \
    o.x = f2bf((V.x - mean) * rs * gv.x + bv.x); \
    o.y = f2bf((V.y - mean) * rs * gv.y + bv.y); \
    o.z = f2bf((V.z - mean) * rs * gv.z + bv.z); \
    o.w = f2bf((V.w - mean) * rs * gv.w + bv.w); \
    *(u16x4*)&out[lane * 4 + OFFS] = o; }
  LNSTORE(v0, 0)
  LNSTORE(v1, 256)
  LNSTORE(v2, 512)
#undef LNSTORE
}

__global__ __launch_bounds__(256) void ln_dual(
    const float* __restrict__ in1, const float* __restrict__ g1, const float* __restrict__ b1,
    u16* __restrict__ out1, int rows1,
    const float* __restrict__ in2, const float* __restrict__ g2, const float* __restrict__ b2,
    u16* __restrict__ out2)
{
  ln_rows4(in1, g1, b1, out1, rows1, in2, g2, b2, out2, blockIdx.x);
}

// ---------------------------------------------------------------------------
// prep: weights->bf16 convert (segs 0-9) + LN1 + bias pack, one launch
// ---------------------------------------------------------------------------
struct PrepArgs {
  const float* csrc[10]; u16* cdst[10]; int cn[10];
  const float* z; const float* zg; const float* zb; u16* zo;
  const float* x; const float* xg; const float* xb; u16* xo;
  const float* zq; const float* zkv; const float* xq; const float* xkv;
  float* bz; float* bx;
};

__global__ __launch_bounds__(256) void prep(PrepArgs a) {
  const int b = blockIdx.x;
  if (b < 23040) {
    const int seg = b / 2304;
    const long i = ((long)(b % 2304) * 256 + threadIdx.x) * 4;
    if (i >= a.cn[seg]) return;
    float4 v = *(const float4*)&a.csrc[seg][i];
    u16x4 o;
    o.x = f2bf(v.x); o.y = f2bf(v.y); o.z = f2bf(v.z); o.w = f2bf(v.w);
    *(u16x4*)&a.cdst[seg][i] = o;
  } else if (b < 28160) {
    ln_rows4(a.z, a.zg, a.zb, a.zo, 4096, a.x, a.xg, a.xb, a.xo, b - 23040);
  } else {
    const int i = (b - 28160) * 256 + threadIdx.x;
    if (i >= 2304) return;
    a.bz[i] = (i < 768) ? a.zq[i] : a.zkv[i - 768];
    a.bx[i] = (i < 768) ? a.xq[i] : a.xkv[i - 768];
  }
}

// ---------------------------------------------------------------------------
// gemm6 core (r10 proven): 256x128 tile, BK=32, 8 waves, per-wave 64x64,
// acc 4x4, 3 LDS buffers (72 KB -> 2 blocks/CU, 16 waves/CU), depth-2
// counted waits (vmcnt(3)+lgkmcnt(0)), setprio around MFMA.
// ---------------------------------------------------------------------------
template<int EPI>
__device__ __forceinline__ void gemm6_core(
    const u16* __restrict__ A, const u16* __restrict__ W,
    const float* __restrict__ bias, const float* __restrict__ res,
    void* __restrict__ outp, long row0, long col0, int N, int K)
{
  __shared__ __align__(16) u16 As[3][256 * 32];
  __shared__ __align__(16) u16 Bs[3][128 * 32];

  const int tid = threadIdx.x;      // 0..511
  const int lane = tid & 63;
  const int w = tid >> 6;           // 0..7
  const int wm = w >> 1;            // 0..3
  const int wn = w & 1;             // 0..1

  const u16* gA[2];
  const u16* gB;
#pragma unroll
  for (int l = 0; l < 2; ++l) {
    const int e = l * 512 + tid;
    const int r = e >> 2, sl = e & 3;
    gA[l] = A + (row0 + r) * (long)K + ((sl ^ ((r >> 1) & 3)) * 8);
  }
  {
    const int r = tid >> 2, sl = tid & 3;
    gB = W + (col0 + r) * (long)K + ((sl ^ ((r >> 1) & 3)) * 8);
  }

  const int fr = lane & 15;
  const int g = lane >> 4;

  f32x4 acc[4][4];
#pragma unroll
  for (int m = 0; m < 4; ++m)
#pragma unroll
    for (int n = 0; n < 4; ++n) acc[m][n] = (f32x4){0.f, 0.f, 0.f, 0.f};

  auto stage = [&](u16* ab, u16* bb, long ko) {
#pragma unroll
    for (int l = 0; l < 2; ++l) async16(gA[l] + ko, &ab[(l * 512 + tid) * 8]);
    async16(gB + ko, &bb[tid * 8]);
  };

  const int nt = K / 32;
  u16 *a0 = &As[0][0], *a1 = &As[1][0], *a2 = &As[2][0];
  u16 *b0 = &Bs[0][0], *b1 = &Bs[1][0], *b2 = &Bs[2][0];

  stage(a0, b0, 0);
  stage(a1, b1, 32);
  SCHED0;
  asm volatile("s_waitcnt vmcnt(3)" ::: "memory");
  BARRIER;
  SCHED0;

  for (int t = 0; t < nt; ++t) {
    if (t + 2 < nt) stage(a2, b2, (long)(t + 2) * 32);
    SCHED0;
    bf16x8 bfr[4];
#pragma unroll
    for (int n = 0; n < 4; ++n) {
      const int r = wn * 64 + n * 16 + fr;
      bfr[n] = *(const bf16x8*)&b0[r * 32 + ((g ^ ((r >> 1) & 3)) * 8)];
    }
    __builtin_amdgcn_s_setprio(1);
#pragma unroll
    for (int m = 0; m < 4; ++m) {
      const int r = wm * 64 + m * 16 + fr;
      bf16x8 af = *(const bf16x8*)&a0[r * 32 + ((g ^ ((r >> 1) & 3)) * 8)];
#pragma unroll
      for (int n = 0; n < 4; ++n)
        acc[m][n] = __builtin_amdgcn_mfma_f32_16x16x32_bf16(af, bfr[n], acc[m][n], 0, 0, 0);
    }
    __builtin_amdgcn_s_setprio(0);
    SCHED0;
    if (t + 2 < nt) {
      asm volatile("s_waitcnt vmcnt(3) lgkmcnt(0)" ::: "memory");
    } else if (t + 1 < nt) {
      asm volatile("s_waitcnt vmcnt(0) lgkmcnt(0)" ::: "memory");
    }
    if (t + 1 < nt) { BARRIER; SCHED0; }
    u16* ta = a0; a0 = a1; a1 = a2; a2 = ta;
    u16* tb = b0; b0 = b1; b1 = b2; b2 = tb;
  }

  float bv[4];
#pragma unroll
  for (int n = 0; n < 4; ++n) bv[n] = bias[col0 + wn * 64 + n * 16 + fr];
#pragma unroll
  for (int m = 0; m < 4; ++m) {
#pragma unroll
    for (int j = 0; j < 4; ++j) {
      const long row = row0 + wm * 64 + m * 16 + g * 4 + j;
      const long base = row * N + col0 + wn * 64 + fr;
#pragma unroll
      for (int n = 0; n < 4; ++n) {
        float v = acc[m][n][j] + bv[n];
        if constexpr (EPI == 0) {
          ((u16*)outp)[base + n * 16] = f2bf(v);
        } else if constexpr (EPI == 1) {
          ((u16*)outp)[base + n * 16] = f2bf(gelu_f(v));
        } else {
          ((float*)outp)[base + n * 16] = v + res[base + n * 16];
        }
      }
    }
  }
}

template<int EPI>
__global__ __launch_bounds__(512, 4) void gemm6f(
    const u16* __restrict__ A0, const u16* __restrict__ W0,
    const float* __restrict__ bias0, const float* __restrict__ res0, void* __restrict__ out0,
    const u16* __restrict__ A1, const u16* __restrict__ W1,
    const float* __restrict__ bias1, const float* __restrict__ res1, void* __restrict__ out1,
    int Y0, int N, int K)
{
  int flat = blockIdx.y * gridDim.x + blockIdx.x;
  const int nwg = gridDim.x * gridDim.y;
  if ((nwg & 7) == 0) flat = (flat & 7) * (nwg >> 3) + (flat >> 3);
  const int bx = flat % gridDim.x;
  const int by = flat / gridDim.x;
  if (by < Y0) {
    gemm6_core<EPI>(A0, W0, bias0, res0, out0, (long)by * 256, (long)bx * 128, N, K);
  } else {
    gemm6_core<EPI>(A1, W1, bias1, res1, out1, (long)(by - Y0) * 256, (long)bx * 128, N, K);
  }
}

// ---------------------------------------------------------------------------
// gemm9 core: 128x128 tile, BK=32, 4 waves, per-wave 64x64, acc 4x4,
// 2 LDS buffers (32 KB). __launch_bounds__(256,5): 5 blocks x 32 KB = 160 KB
// exactly -> target 5 blocks/CU = 20 waves/CU (the one confirmed lever).
// Drain sync (r6-proven): stage(t+1) at step top, one __syncthreads/step.
// ---------------------------------------------------------------------------
template<int EPI>
__device__ __forceinline__ void gemm9_core(
    const u16* __restrict__ A, const u16* __restrict__ W,
    const float* __restrict__ bias, const float* __restrict__ res,
    void* __restrict__ outp, long row0, long col0, int N, int K)
{
  __shared__ __align__(16) u16 As[2][128 * 32];
  __shared__ __align__(16) u16 Bs[2][128 * 32];

  const int tid = threadIdx.x;      // 0..255
  const int lane = tid & 63;
  const int w = tid >> 6;           // 0..3
  const int wm = w >> 1;            // 0..1
  const int wn = w & 1;             // 0..1

  const u16* gA[2];
  const u16* gB[2];
#pragma unroll
  for (int l = 0; l < 2; ++l) {
    const int e = l * 256 + tid;
    const int r = e >> 2, sl = e & 3;
    gA[l] = A + (row0 + r) * (long)K + ((sl ^ ((r >> 1) & 3)) * 8);
    gB[l] = W + (col0 + r) * (long)K + ((sl ^ ((r >> 1) & 3)) * 8);
  }

  const int fr = lane & 15;
  const int g = lane >> 4;

  f32x4 acc[4][4];
#pragma unroll
  for (int m = 0; m < 4; ++m)
#pragma unroll
    for (int n = 0; n < 4; ++n) acc[m][n] = (f32x4){0.f, 0.f, 0.f, 0.f};

  auto stage = [&](int buf, long ko) {
#pragma unroll
    for (int l = 0; l < 2; ++l) {
      async16(gA[l] + ko, &As[buf][(l * 256 + tid) * 8]);
      async16(gB[l] + ko, &Bs[buf][(l * 256 + tid) * 8]);
    }
  };

  const int nt = K / 32;
  stage(0, 0);
  __syncthreads();

  int cur = 0;
  for (int t = 0; t < nt; ++t) {
    if (t + 1 < nt) stage(cur ^ 1, (long)(t + 1) * 32);
    const u16* Ab = As[cur];
    const u16* Bb = Bs[cur];
    bf16x8 bfr[4];
#pragma unroll
    for (int n = 0; n < 4; ++n) {
      const int r = wn * 64 + n * 16 + fr;
      bfr[n] = *(const bf16x8*)&Bb[r * 32 + ((g ^ ((r >> 1) & 3)) * 8)];
    }
    __builtin_amdgcn_s_setprio(1);
#pragma unroll
    for (int m = 0; m < 4; ++m) {
      const int r = wm * 64 + m * 16 + fr;
      bf16x8 af = *(const bf16x8*)&Ab[r * 32 + ((g ^ ((r >> 1) & 3)) * 8)];
#pragma unroll
      for (int n = 0; n < 4; ++n)
        acc[m][n] = __builtin_amdgcn_mfma_f32_16x16x32_bf16(af, bfr[n], acc[m][n], 0, 0, 0);
    }
    __builtin_amdgcn_s_setprio(0);
    __syncthreads();
    cur ^= 1;
  }

  float bv[4];
#pragma unroll
  for (int n = 0; n < 4; ++n) bv[n] = bias[col0 + wn * 64 + n * 16 + fr];
#pragma unroll
  for (int m = 0; m < 4; ++m) {
#pragma unroll
    for (int j = 0; j < 4; ++j) {
      const long row = row0 + wm * 64 + m * 16 + g * 4 + j;
      const long base = row * N + col0 + wn * 64 + fr;
#pragma unroll
      for (int n = 0; n < 4; ++n) {
        float v = acc[m][n][j] + bv[n];
        if constexpr (EPI == 0) {
          ((u16*)outp)[base + n * 16] = f2bf(v);
        } else if constexpr (EPI == 1) {
          ((u16*)outp)[base + n * 16] = f2bf(gelu_f(v));
        } else {
          ((float*)outp)[base + n * 16] = v + res[base + n * 16];
        }
      }
    }
  }
}

template<int EPI>
__global__ __launch_bounds__(256, 5) void gemm9(
    const u16* __restrict__ A, const u16* __restrict__ W,
    const float* __restrict__ bias, const float* __restrict__ res,
    void* __restrict__ outp, int M, int N, int K)
{
  int flat = blockIdx.y * gridDim.x + blockIdx.x;
  const int nwg = gridDim.x * gridDim.y;
  if ((nwg & 7) == 0) flat = (flat & 7) * (nwg >> 3) + (flat >> 3);
  const int bx = flat % gridDim.x;
  const int by = flat / gridDim.x;
  gemm9_core<EPI>(A, W, bias, res, outp, (long)by * 128, (long)bx * 128, N, K);
}

template<int EPI>
__global__ __launch_bounds__(256, 5) void gemm9f(
    const u16* __restrict__ A0, const u16* __restrict__ W0,
    const float* __restrict__ bias0, const float* __restrict__ res0, void* __restrict__ out0,
    const u16* __restrict__ A1, const u16* __restrict__ W1,
    const float* __restrict__ bias1, const float* __restrict__ res1, void* __restrict__ out1,
    int Y0, int N, int K)
{
  int flat = blockIdx.y * gridDim.x + blockIdx.x;
  const int nwg = gridDim.x * gridDim.y;
  if ((nwg & 7) == 0) flat = (flat & 7) * (nwg >> 3) + (flat >> 3);
  const int bx = flat % gridDim.x;
  const int by = flat / gridDim.x;
  if (by < Y0) {
    gemm9_core<EPI>(A0, W0, bias0, res0, out0, (long)by * 128, (long)bx * 128, N, K);
  } else {
    gemm9_core<EPI>(A1, W1, bias1, res1, out1, (long)(by - Y0) * 128, (long)bx * 128, N, K);
  }
}

// ---------------------------------------------------------------------------
// Relative position index (matches _rel_index in reference)
// ---------------------------------------------------------------------------
template<int LQ>
__device__ __forceinline__ int rel_index(int q, int k) {
  if constexpr (LQ == 64) {
    const int qh = q >> 3, qw = q & 7, kh = k >> 4, kw = k & 15;
    return (qh - kh + 15) * 23 + (qw - kw + 15);
  } else {
    const int qh = q >> 4, qw = q & 15, kh = k >> 3, kw = k & 7;
    return (qh - kh + 7) * 23 + (qw - kw + 7);
  }
}

// ---------------------------------------------------------------------------
// Fused cross attention core (16x16 MFMA), dynamic shared, Ps aliased:
//  ALIAS=0: Ps overlays Qs (per-wave self-alias, x-path).
//  ALIAS=1: Ps overlays Ks (z-path; +1 barrier after QK^T).
// ---------------------------------------------------------------------------
template<int LQ, int LK, int ALIAS>
__device__ void attn_core(
    const u16* __restrict__ Q, int qs, const u16* __restrict__ KV, int ks,
    const float* __restrict__ rpb, u16* __restrict__ O, char* sm, int h, int b)
{
  constexpr int MT = LQ / 64;
  constexpr int NT = LK / 16;
  constexpr int KSPV = LK / 32;
  static_assert(LQ * LK == (ALIAS == 0 ? LQ * 64 : LK * 64), "alias size");

  u16* Qs = (u16*)sm;                      // LQ*64
  u16* Ks = Qs + LQ * 64;                  // LK*64
  u16* Vt = Ks + LK * 64;                  // 64*LK
  float* bias_s = (float*)(Vt + 64 * LK);  // 529
  u16* Ps = (ALIAS == 0) ? Qs : Ks;        // LQ*LK (aliased)

  const int tid = threadIdx.x;
  const int lane = tid & 63;
  const int w = tid >> 6;

  for (int i = tid; i < 529; i += 256) bias_s[i] = rpb[i * 12 + h];

#pragma unroll
  for (int it = 0; it < LQ * 8 / 256; ++it) {
    const int s = it * 256 + tid;
    const int r = s >> 3, sl2 = s & 7;
    bf16x8 v = *(const bf16x8*)&Q[(size_t)(b * LQ + r) * qs + h * 64 + sl2 * 8];
    *(bf16x8*)&Qs[r * 64 + ((sl2 ^ (r & 7)) * 8)] = v;
  }
#pragma unroll
  for (int it = 0; it < LK * 8 / 256; ++it) {
    const int s = it * 256 + tid;
    const int r = s >> 3, sl2 = s & 7;
    bf16x8 v = *(const bf16x8*)&KV[(size_t)(b * LK + r) * ks + h * 64 + sl2 * 8];
    *(bf16x8*)&Ks[r * 64 + ((sl2 ^ (r & 7)) * 8)] = v;
  }
#pragma unroll
  for (int it = 0; it < LK * 8 / 256; ++it) {
    const int s = it * 256 + tid;
    const int r = s >> 3, sl2 = s & 7;
    const int d0 = sl2 * 8;
    bf16x8 v = *(const bf16x8*)&KV[(size_t)(b * LK + r) * ks + 768 + h * 64 + d0];
#pragma unroll
    for (int j = 0; j < 8; ++j) {
      const int d = d0 + j;
      Vt[d * LK + (((r >> 3) ^ (d & 7)) * 8) + (r & 7)] = (u16)v[j];
    }
  }
  __syncthreads();

  const int fr = lane & 15;
  const int g = lane >> 4;
  const int qbase = w * MT * 16;

  f32x4 sacc[MT][NT];
#pragma unroll
  for (int mt = 0; mt < MT; ++mt)
#pragma unroll
    for (int nt = 0; nt < NT; ++nt) sacc[mt][nt] = (f32x4){0.f, 0.f, 0.f, 0.f};

#pragma unroll
  for (int mt = 0; mt < MT; ++mt) {
    const int qr = qbase + mt * 16 + fr;
    bf16x8 aq0 = *(const bf16x8*)&Qs[qr * 64 + (((0 + g) ^ (qr & 7)) * 8)];
    bf16x8 aq1 = *(const bf16x8*)&Qs[qr * 64 + (((4 + g) ^ (qr & 7)) * 8)];
#pragma unroll
    for (int nt = 0; nt < NT; ++nt) {
      const int kr = nt * 16 + fr;
      bf16x8 bk0 = *(const bf16x8*)&Ks[kr * 64 + (((0 + g) ^ (kr & 7)) * 8)];
      bf16x8 bk1 = *(const bf16x8*)&Ks[kr * 64 + (((4 + g) ^ (kr & 7)) * 8)];
      sacc[mt][nt] = __builtin_amdgcn_mfma_f32_16x16x32_bf16(aq0, bk0, sacc[mt][nt], 0, 0, 0);
      sacc[mt][nt] = __builtin_amdgcn_mfma_f32_16x16x32_bf16(aq1, bk1, sacc[mt][nt], 0, 0, 0);
    }
  }

  if (ALIAS == 1) __syncthreads();   // all Ks reads done before Ps overwrites

#pragma unroll
  for (int mt = 0; mt < MT; ++mt) {
#pragma unroll
    for (int reg = 0; reg < 4; ++reg) {
      const int q = qbase + mt * 16 + g * 4 + reg;
      float mx = -3.0e38f;
#pragma unroll
      for (int nt = 0; nt < NT; ++nt) {
        const int k = nt * 16 + fr;
        float s = sacc[mt][nt][reg] * 0.125f + bias_s[rel_index<LQ>(q, k)];
        sacc[mt][nt][reg] = s;
        mx = fmaxf(mx, s);
      }
      mx = fmaxf(mx, __shfl_xor(mx, 1));
      mx = fmaxf(mx, __shfl_xor(mx, 2));
      mx = fmaxf(mx, __shfl_xor(mx, 4));
      mx = fmaxf(mx, __shfl_xor(mx, 8));
      float sum = 0.f;
#pragma unroll
      for (int nt = 0; nt < NT; ++nt) {
        float p = __expf(sacc[mt][nt][reg] - mx);
        sacc[mt][nt][reg] = p;
        sum += p;
      }
      sum += __shfl_xor(sum, 1);
      sum += __shfl_xor(sum, 2);
      sum += __shfl_xor(sum, 4);
      sum += __shfl_xor(sum, 8);
      const float inv = 1.0f / sum;
#pragma unroll
      for (int nt = 0; nt < NT; ++nt) {
        const int k = nt * 16 + fr;
        Ps[q * LK + (((k >> 3) ^ (q & 7)) * 8) + (k & 7)] = f2bf(sacc[mt][nt][reg] * inv);
      }
    }
  }
  __syncthreads();

  f32x4 oacc[MT][4];
#pragma unroll
  for (int mt = 0; mt < MT; ++mt)
#pragma unroll
    for (int n = 0; n < 4; ++n) oacc[mt][n] = (f32x4){0.f, 0.f, 0.f, 0.f};

#pragma unroll
  for (int mt = 0; mt < MT; ++mt) {
    const int pr = qbase + mt * 16 + fr;
#pragma unroll
    for (int ks2 = 0; ks2 < KSPV; ++ks2) {
      bf16x8 ap = *(const bf16x8*)&Ps[pr * LK + (((ks2 * 4 + g) ^ (pr & 7)) * 8)];
#pragma unroll
      for (int n = 0; n < 4; ++n) {
        const int d = n * 16 + fr;
        bf16x8 bvv = *(const bf16x8*)&Vt[d * LK + (((ks2 * 4 + g) ^ (d & 7)) * 8)];
        oacc[mt][n] = __builtin_amdgcn_mfma_f32_16x16x32_bf16(ap, bvv, oacc[mt][n], 0, 0, 0);
      }
    }
  }

#pragma unroll
  for (int mt = 0; mt < MT; ++mt)
#pragma unroll
    for (int n = 0; n < 4; ++n)
#pragma unroll
      for (int reg = 0; reg < 4; ++reg) {
        const int q = qbase + mt * 16 + g * 4 + reg;
        const int d = n * 16 + fr;
        O[(size_t)(b * LQ + q) * 768 + h * 64 + d] = f2bf(oacc[mt][n][reg]);
      }
}

template<int LQ, int LK, int ALIAS>
__global__ __launch_bounds__(256) void attn_one(
    const u16* __restrict__ Q, int qs, const u16* __restrict__ KV, int ks,
    const float* __restrict__ rpb, u16* __restrict__ O)
{
  extern __shared__ __align__(16) char smdyn[];
  attn_core<LQ, LK, ALIAS>(Q, qs, KV, ks, rpb, O, smdyn, blockIdx.x, blockIdx.y);
}

// ---------------------------------------------------------------------------
// Host launcher
// ---------------------------------------------------------------------------
extern "C" void kernel_launch(void* const* d_in, const int* in_sizes, int n_in,
                              void* d_out, int out_size, void* d_ws, size_t ws_size,
                              hipStream_t stream)
{
  const float* z      = (const float*)d_in[0];
  const float* x      = (const float*)d_in[1];
  const float* zln1g  = (const float*)d_in[2];
  const float* zln1b  = (const float*)d_in[3];
  const float* xln1g  = (const float*)d_in[4];
  const float* xln1b  = (const float*)d_in[5];
  const float* zx_qw  = (const float*)d_in[6];
  const float* zx_qb  = (const float*)d_in[7];
  const float* zx_kvw = (const float*)d_in[8];
  const float* zx_kvb = (const float*)d_in[9];
  const float* zx_pw  = (const float*)d_in[10];
  const float* zx_pb  = (const float*)d_in[11];
  const float* zx_rpb = (const float*)d_in[12];
  const float* xz_qw  = (const float*)d_in[13];
  const float* xz_qb  = (const float*)d_in[14];
  const float* xz_kvw = (const float*)d_in[15];
  const float* xz_kvb = (const float*)d_in[16];
  const float* xz_pw  = (const float*)d_in[17];
  const float* xz_pb  = (const float*)d_in[18];
  const float* xz_rpb = (const float*)d_in[19];
  const float* zln2g  = (const float*)d_in[20];
  const float* zln2b  = (const float*)d_in[21];
  const float* zfc1w  = (const float*)d_in[22];
  const float* zfc1b  = (const float*)d_in[23];
  const float* zfc2w  = (const float*)d_in[24];
  const float* zfc2b  = (const float*)d_in[25];
  const float* xln2g  = (const float*)d_in[26];
  const float* xln2b  = (const float*)d_in[27];
  const float* xfc1w  = (const float*)d_in[28];
  const float* xfc1b  = (const float*)d_in[29];
  const float* xfc2w  = (const float*)d_in[30];
  const float* xfc2b  = (const float*)d_in[31];

  float* out = (float*)d_out;
  float* z2 = out;                       // 4096 x 768 f32
  float* x2 = out + 3145728;             // 16384 x 768 f32

  char* ws = (char*)d_ws;
  size_t off = 0;
  auto take = [&](size_t bytes) {
    char* p = ws + off;
    off += (bytes + 255) & ~(size_t)255;
    return p;
  };
  u16* w_zn   = (u16*)take(1769472 * 2);   // [zx_qw ; xz_kvw]  (2304 x 768)
  u16* w_xn   = (u16*)take(1769472 * 2);   // [xz_qw ; zx_kvw]
  u16* w_zx_p = (u16*)take(589824 * 2);
  u16* w_xz_p = (u16*)take(589824 * 2);
  u16* w_zfc1 = (u16*)take(2359296 * 2);
  u16* w_zfc2 = (u16*)take(2359296 * 2);
  u16* w_xfc1 = (u16*)take(2359296 * 2);
  u16* w_xfc2 = (u16*)take(2359296 * 2);
  float* b_zn = (float*)take(2304 * 4);
  float* b_xn = (float*)take(2304 * 4);
  u16* regA   = (u16*)take(31457280);      // zn|xn -> ao_z|ao_x -> z2n|x2n

  const size_t need_full = off + 125829120;
  const bool full = (ws_size >= need_full);
  u16* regB = (u16*)take(full ? 125829120 : 94371840);

  u16* zn    = regA;
  u16* xn    = regA + 3145728;
  u16* qkv_z = regB;                        // 4096 x 2304
  u16* qkv_x = regB + 9437184;              // 16384 x 2304
  u16* ao_z  = zn;
  u16* ao_x  = xn;
  u16* z2n   = zn;
  u16* x2n   = xn;
  u16* hz    = regB;                        // 4096 x 3072
  u16* hx    = regB + 12582912;             // 16384 (or 8192) x 3072

  // 1. prep: weight convert + LN1 + bias pack
  PrepArgs a;
  a.csrc[0] = zx_qw;  a.cdst[0] = w_zn;           a.cn[0] = 589824;
  a.csrc[1] = xz_kvw; a.cdst[1] = w_zn + 589824;  a.cn[1] = 1179648;
  a.csrc[2] = xz_qw;  a.cdst[2] = w_xn;           a.cn[2] = 589824;
  a.csrc[3] = zx_kvw; a.cdst[3] = w_xn + 589824;  a.cn[3] = 1179648;
  a.csrc[4] = zx_pw;  a.cdst[4] = w_zx_p;         a.cn[4] = 589824;
  a.csrc[5] = xz_pw;  a.cdst[5] = w_xz_p;         a.cn[5] = 589824;
  a.csrc[6] = zfc1w;  a.cdst[6] = w_zfc1;         a.cn[6] = 2359296;
  a.csrc[7] = zfc2w;  a.cdst[7] = w_zfc2;         a.cn[7] = 2359296;
  a.csrc[8] = xfc1w;  a.cdst[8] = w_xfc1;         a.cn[8] = 2359296;
  a.csrc[9] = xfc2w;  a.cdst[9] = w_xfc2;         a.cn[9] = 2359296;
  a.z = z; a.zg = zln1g; a.zb = zln1b; a.zo = zn;
  a.x = x; a.xg = xln1g; a.xb = xln1b; a.xo = xn;
  a.zq = zx_qb; a.zkv = xz_kvb; a.xq = xz_qb; a.xkv = zx_kvb;
  a.bz = b_zn; a.bx = b_xn;
  prep<<<28169, 256, 0, stream>>>(a);

  // 2. fused packed QKV (gemm6f): zn -> [q_z|kv_z], xn -> [q_x|kv_x]
  gemm6f<0><<<dim3(18, 80), 512, 0, stream>>>(
      zn, w_zn, b_zn, nullptr, qkv_z,
      xn, w_xn, b_xn, nullptr, qkv_x, 16, 2304, 768);

  // 3. attention, dynamic-LDS sized per path (z: 75.8 KB -> 2/CU, x: 51.3 KB -> 3/CU)
  constexpr u32 SZ_Z = (64 * 64 + 256 * 64 + 64 * 256) * 2 + 529 * 4;   // 75844
  constexpr u32 SZ_X = (256 * 64 + 64 * 64 + 64 * 64) * 2 + 529 * 4;    // 51268
  attn_one<64, 256, 1><<<dim3(12, 64), 256, SZ_Z, stream>>>(qkv_z, 2304, qkv_x + 768, 2304, zx_rpb, ao_z);
  attn_one<256, 64, 0><<<dim3(12, 64), 256, SZ_X, stream>>>(qkv_x, 2304, qkv_z + 768, 2304, xz_rpb, ao_x);

  // 4. fused output proj + residual (gemm6f)
  gemm6f<2><<<dim3(6, 80), 512, 0, stream>>>(
      ao_z, w_zx_p, zx_pb, z, z2,
      ao_x, w_xz_p, xz_pb, x, x2, 16, 768, 768);

  // 5. LN2
  ln_dual<<<5120, 256, 0, stream>>>(z2, zln2g, zln2b, z2n, 4096, x2, xln2g, xln2b, x2n);

  // 6. fused MLPs — gemm9 (128-tile, target 5 blocks/CU = 20 waves/CU)
  if (full) {
    gemm9f<1><<<dim3(24, 160), 256, 0, stream>>>(
        z2n, w_zfc1, zfc1b, nullptr, hz,
        x2n, w_xfc1, xfc1b, nullptr, hx, 32, 3072, 768);
    gemm9f<2><<<dim3(6, 160), 256, 0, stream>>>(
        hz, w_zfc2, zfc2b, z2, z2,
        hx, w_xfc2, xfc2b, x2, x2, 32, 768, 3072);
  } else {
    gemm9f<1><<<dim3(24, 96), 256, 0, stream>>>(
        z2n, w_zfc1, zfc1b, nullptr, hz,
        x2n, w_xfc1, xfc1b, nullptr, hx, 32, 3072, 768);
    gemm9f<2><<<dim3(6, 96), 256, 0, stream>>>(
        hz, w_zfc2, zfc2b, z2, z2,
        hx, w_xfc2, xfc2b, x2, x2, 32, 768, 3072);
    gemm9<1><<<dim3(24, 64), 256, 0, stream>>>(x2n + (size_t)8192 * 768, w_xfc1, xfc1b, nullptr, hx, 8192, 3072, 768);
    gemm9<2><<<dim3(6, 64), 256, 0, stream>>>(hx, w_xfc2, xfc2b, x2 + (size_t)8192 * 768, x2 + (size_t)8192 * 768, 8192, 768, 3072);
  }
}

// Round 17
// 503.860 us; speedup vs baseline: 1.5561x; 1.5561x over previous
//
#include <hip/hip_runtime.h>
#include <math.h>

typedef unsigned short u16;
typedef unsigned int u32;
typedef __attribute__((ext_vector_type(8))) short bf16x8;
typedef __attribute__((ext_vector_type(4))) float f32x4;
typedef __attribute__((ext_vector_type(4))) u16 u16x4;

__device__ __forceinline__ u16 f2bf(float f) {
  u32 u = __builtin_bit_cast(u32, f);
  u32 r = (u + 0x7fffu + ((u >> 16) & 1u)) >> 16;
  return (u16)r;
}

// fast gelu: v*sigmoid(1.5957691*v*(1+0.044715*v^2)); |err|<3e-3 << 0.1175 thr
__device__ __forceinline__ float gelu_f(float v) {
  float u = 1.5957691216057308f * v * (1.0f + 0.044715f * v * v);
  return v / (1.0f + __expf(-u));
}

__device__ __forceinline__ void async16(const void* g, void* l) {
  __builtin_amdgcn_global_load_lds(
      (__attribute__((address_space(1))) void*)(unsigned long long)(const char*)g,
      (__attribute__((address_space(3))) void*)l, 16, 0, 0);
}

#define SCHED0 __builtin_amdgcn_sched_barrier(0)
#define BARRIER __builtin_amdgcn_s_barrier()

// ---------------------------------------------------------------------------
// LayerNorm row-block body (4 rows, 4 waves), f32 in -> bf16 out
// ---------------------------------------------------------------------------
__device__ __forceinline__ void ln_rows4(
    const float* __restrict__ in1, const float* __restrict__ g1, const float* __restrict__ b1,
    u16* __restrict__ out1, int rows1,
    const float* __restrict__ in2, const float* __restrict__ g2v, const float* __restrict__ b2v,
    u16* __restrict__ out2, int rowblk)
{
  const int w = threadIdx.x >> 6;
  const int lane = threadIdx.x & 63;
  const int row = rowblk * 4 + w;
  const float* in; const float* gg; const float* bb; u16* out;
  if (row < rows1) { in = in1 + (size_t)row * 768; gg = g1; bb = b1; out = out1 + (size_t)row * 768; }
  else { const int r2 = row - rows1; in = in2 + (size_t)r2 * 768; gg = g2v; bb = b2v; out = out2 + (size_t)r2 * 768; }

  float4 v0 = *(const float4*)&in[lane * 4];
  float4 v1 = *(const float4*)&in[lane * 4 + 256];
  float4 v2 = *(const float4*)&in[lane * 4 + 512];
  float s = v0.x + v0.y + v0.z + v0.w + v1.x + v1.y + v1.z + v1.w + v2.x + v2.y + v2.z + v2.w;
  float s2 = v0.x*v0.x + v0.y*v0.y + v0.z*v0.z + v0.w*v0.w
           + v1.x*v1.x + v1.y*v1.y + v1.z*v1.z + v1.w*v1.w
           + v2.x*v2.x + v2.y*v2.y + v2.z*v2.z + v2.w*v2.w;
#pragma unroll
  for (int m = 1; m <= 32; m <<= 1) { s += __shfl_xor(s, m); s2 += __shfl_xor(s2, m); }
  const float mean = s * (1.0f / 768.0f);
  const float var = s2 * (1.0f / 768.0f) - mean * mean;
  const float rs = rsqrtf(var + 1e-5f);

#define LNSTORE(V, OFFS) { \
    float4 gv = *(const float4*)&gg[lane * 4 + OFFS]; \
    float4 bv = *(const float4*)&bb[lane * 4 + OFFS]; \
    u16x4 o; \
    o.x = f2bf((V.x - mean) * rs * gv.x + bv.x); \
    o.y = f2bf((V.y - mean) * rs * gv.y + bv.y); \
    o.z = f2bf((V.z - mean) * rs * gv.z + bv.z); \
    o.w = f2bf((V.w - mean) * rs * gv.w + bv.w); \
    *(u16x4*)&out[lane * 4 + OFFS] = o; }
  LNSTORE(v0, 0)
  LNSTORE(v1, 256)
  LNSTORE(v2, 512)
#undef LNSTORE
}

__global__ __launch_bounds__(256) void ln_dual(
    const float* __restrict__ in1, const float* __restrict__ g1, const float* __restrict__ b1,
    u16* __restrict__ out1, int rows1,
    const float* __restrict__ in2, const float* __restrict__ g2, const float* __restrict__ b2,
    u16* __restrict__ out2)
{
  ln_rows4(in1, g1, b1, out1, rows1, in2, g2, b2, out2, blockIdx.x);
}

// ---------------------------------------------------------------------------
// prep: weights->bf16 convert (segs 0-9) + LN1 + bias pack, one launch
// ---------------------------------------------------------------------------
struct PrepArgs {
  const float* csrc[10]; u16* cdst[10]; int cn[10];
  const float* z; const float* zg; const float* zb; u16* zo;
  const float* x; const float* xg; const float* xb; u16* xo;
  const float* zq; const float* zkv; const float* xq; const float* xkv;
  float* bz; float* bx;
};

__global__ __launch_bounds__(256) void prep(PrepArgs a) {
  const int b = blockIdx.x;
  if (b < 23040) {
    const int seg = b / 2304;
    const long i = ((long)(b % 2304) * 256 + threadIdx.x) * 4;
    if (i >= a.cn[seg]) return;
    float4 v = *(const float4*)&a.csrc[seg][i];
    u16x4 o;
    o.x = f2bf(v.x); o.y = f2bf(v.y); o.z = f2bf(v.z); o.w = f2bf(v.w);
    *(u16x4*)&a.cdst[seg][i] = o;
  } else if (b < 28160) {
    ln_rows4(a.z, a.zg, a.zb, a.zo, 4096, a.x, a.xg, a.xb, a.xo, b - 23040);
  } else {
    const int i = (b - 28160) * 256 + threadIdx.x;
    if (i >= 2304) return;
    a.bz[i] = (i < 768) ? a.zq[i] : a.zkv[i - 768];
    a.bx[i] = (i < 768) ? a.xq[i] : a.xkv[i - 768];
  }
}

// ---------------------------------------------------------------------------
// gemm6 core (r10 proven): 256x128 tile, BK=32, 8 waves, per-wave 64x64,
// acc 4x4, 3 LDS buffers (72 KB -> 2 blocks/CU, 16 waves/CU), depth-2
// counted waits (vmcnt(3)+lgkmcnt(0)), setprio around MFMA.
// ---------------------------------------------------------------------------
template<int EPI>
__device__ __forceinline__ void gemm6_core(
    const u16* __restrict__ A, const u16* __restrict__ W,
    const float* __restrict__ bias, const float* __restrict__ res,
    void* __restrict__ outp, long row0, long col0, int N, int K)
{
  __shared__ __align__(16) u16 As[3][256 * 32];
  __shared__ __align__(16) u16 Bs[3][128 * 32];

  const int tid = threadIdx.x;      // 0..511
  const int lane = tid & 63;
  const int w = tid >> 6;           // 0..7
  const int wm = w >> 1;            // 0..3
  const int wn = w & 1;             // 0..1

  const u16* gA[2];
  const u16* gB;
#pragma unroll
  for (int l = 0; l < 2; ++l) {
    const int e = l * 512 + tid;
    const int r = e >> 2, sl = e & 3;
    gA[l] = A + (row0 + r) * (long)K + ((sl ^ ((r >> 1) & 3)) * 8);
  }
  {
    const int r = tid >> 2, sl = tid & 3;
    gB = W + (col0 + r) * (long)K + ((sl ^ ((r >> 1) & 3)) * 8);
  }

  const int fr = lane & 15;
  const int g = lane >> 4;

  f32x4 acc[4][4];
#pragma unroll
  for (int m = 0; m < 4; ++m)
#pragma unroll
    for (int n = 0; n < 4; ++n) acc[m][n] = (f32x4){0.f, 0.f, 0.f, 0.f};

  auto stage = [&](u16* ab, u16* bb, long ko) {
#pragma unroll
    for (int l = 0; l < 2; ++l) async16(gA[l] + ko, &ab[(l * 512 + tid) * 8]);
    async16(gB + ko, &bb[tid * 8]);
  };

  const int nt = K / 32;
  u16 *a0 = &As[0][0], *a1 = &As[1][0], *a2 = &As[2][0];
  u16 *b0 = &Bs[0][0], *b1 = &Bs[1][0], *b2 = &Bs[2][0];

  stage(a0, b0, 0);
  stage(a1, b1, 32);
  SCHED0;
  asm volatile("s_waitcnt vmcnt(3)" ::: "memory");
  BARRIER;
  SCHED0;

  for (int t = 0; t < nt; ++t) {
    if (t + 2 < nt) stage(a2, b2, (long)(t + 2) * 32);
    SCHED0;
    bf16x8 bfr[4];
#pragma unroll
    for (int n = 0; n < 4; ++n) {
      const int r = wn * 64 + n * 16 + fr;
      bfr[n] = *(const bf16x8*)&b0[r * 32 + ((g ^ ((r >> 1) & 3)) * 8)];
    }
    __builtin_amdgcn_s_setprio(1);
#pragma unroll
    for (int m = 0; m < 4; ++m) {
      const int r = wm * 64 + m * 16 + fr;
      bf16x8 af = *(const bf16x8*)&a0[r * 32 + ((g ^ ((r >> 1) & 3)) * 8)];
#pragma unroll
      for (int n = 0; n < 4; ++n)
        acc[m][n] = __builtin_amdgcn_mfma_f32_16x16x32_bf16(af, bfr[n], acc[m][n], 0, 0, 0);
    }
    __builtin_amdgcn_s_setprio(0);
    SCHED0;
    if (t + 2 < nt) {
      asm volatile("s_waitcnt vmcnt(3) lgkmcnt(0)" ::: "memory");
    } else if (t + 1 < nt) {
      asm volatile("s_waitcnt vmcnt(0) lgkmcnt(0)" ::: "memory");
    }
    if (t + 1 < nt) { BARRIER; SCHED0; }
    u16* ta = a0; a0 = a1; a1 = a2; a2 = ta;
    u16* tb = b0; b0 = b1; b1 = b2; b2 = tb;
  }

  float bv[4];
#pragma unroll
  for (int n = 0; n < 4; ++n) bv[n] = bias[col0 + wn * 64 + n * 16 + fr];
#pragma unroll
  for (int m = 0; m < 4; ++m) {
#pragma unroll
    for (int j = 0; j < 4; ++j) {
      const long row = row0 + wm * 64 + m * 16 + g * 4 + j;
      const long base = row * N + col0 + wn * 64 + fr;
#pragma unroll
      for (int n = 0; n < 4; ++n) {
        float v = acc[m][n][j] + bv[n];
        if constexpr (EPI == 0) {
          ((u16*)outp)[base + n * 16] = f2bf(v);
        } else if constexpr (EPI == 1) {
          ((u16*)outp)[base + n * 16] = f2bf(gelu_f(v));
        } else {
          ((float*)outp)[base + n * 16] = v + res[base + n * 16];
        }
      }
    }
  }
}

template<int EPI>
__global__ __launch_bounds__(512, 4) void gemm6f(
    const u16* __restrict__ A0, const u16* __restrict__ W0,
    const float* __restrict__ bias0, const float* __restrict__ res0, void* __restrict__ out0,
    const u16* __restrict__ A1, const u16* __restrict__ W1,
    const float* __restrict__ bias1, const float* __restrict__ res1, void* __restrict__ out1,
    int Y0, int N, int K)
{
  int flat = blockIdx.y * gridDim.x + blockIdx.x;
  const int nwg = gridDim.x * gridDim.y;
  if ((nwg & 7) == 0) flat = (flat & 7) * (nwg >> 3) + (flat >> 3);
  const int bx = flat % gridDim.x;
  const int by = flat / gridDim.x;
  if (by < Y0) {
    gemm6_core<EPI>(A0, W0, bias0, res0, out0, (long)by * 256, (long)bx * 128, N, K);
  } else {
    gemm6_core<EPI>(A1, W1, bias1, res1, out1, (long)(by - Y0) * 256, (long)bx * 128, N, K);
  }
}

// ---------------------------------------------------------------------------
// gemm9 core: 128x128 tile, BK=32, 4 waves, per-wave 64x64, acc 4x4,
// 2 LDS buffers (32 KB -> 4 blocks/CU, 16 waves/CU). Drain sync (r6-proven):
// stage(t+1) at step top, one __syncthreads at step end.
// NOTE: (256,5) tried r16 -> forced 48 VGPR -> scratch spill, -80%. Keep 4.
// ---------------------------------------------------------------------------
template<int EPI>
__device__ __forceinline__ void gemm9_core(
    const u16* __restrict__ A, const u16* __restrict__ W,
    const float* __restrict__ bias, const float* __restrict__ res,
    void* __restrict__ outp, long row0, long col0, int N, int K)
{
  __shared__ __align__(16) u16 As[2][128 * 32];
  __shared__ __align__(16) u16 Bs[2][128 * 32];

  const int tid = threadIdx.x;      // 0..255
  const int lane = tid & 63;
  const int w = tid >> 6;           // 0..3
  const int wm = w >> 1;            // 0..1
  const int wn = w & 1;             // 0..1

  const u16* gA[2];
  const u16* gB[2];
#pragma unroll
  for (int l = 0; l < 2; ++l) {
    const int e = l * 256 + tid;
    const int r = e >> 2, sl = e & 3;
    gA[l] = A + (row0 + r) * (long)K + ((sl ^ ((r >> 1) & 3)) * 8);
    gB[l] = W + (col0 + r) * (long)K + ((sl ^ ((r >> 1) & 3)) * 8);
  }

  const int fr = lane & 15;
  const int g = lane >> 4;

  f32x4 acc[4][4];
#pragma unroll
  for (int m = 0; m < 4; ++m)
#pragma unroll
    for (int n = 0; n < 4; ++n) acc[m][n] = (f32x4){0.f, 0.f, 0.f, 0.f};

  auto stage = [&](int buf, long ko) {
#pragma unroll
    for (int l = 0; l < 2; ++l) {
      async16(gA[l] + ko, &As[buf][(l * 256 + tid) * 8]);
      async16(gB[l] + ko, &Bs[buf][(l * 256 + tid) * 8]);
    }
  };

  const int nt = K / 32;
  stage(0, 0);
  __syncthreads();

  int cur = 0;
  for (int t = 0; t < nt; ++t) {
    if (t + 1 < nt) stage(cur ^ 1, (long)(t + 1) * 32);
    const u16* Ab = As[cur];
    const u16* Bb = Bs[cur];
    bf16x8 bfr[4];
#pragma unroll
    for (int n = 0; n < 4; ++n) {
      const int r = wn * 64 + n * 16 + fr;
      bfr[n] = *(const bf16x8*)&Bb[r * 32 + ((g ^ ((r >> 1) & 3)) * 8)];
    }
    __builtin_amdgcn_s_setprio(1);
#pragma unroll
    for (int m = 0; m < 4; ++m) {
      const int r = wm * 64 + m * 16 + fr;
      bf16x8 af = *(const bf16x8*)&Ab[r * 32 + ((g ^ ((r >> 1) & 3)) * 8)];
#pragma unroll
      for (int n = 0; n < 4; ++n)
        acc[m][n] = __builtin_amdgcn_mfma_f32_16x16x32_bf16(af, bfr[n], acc[m][n], 0, 0, 0);
    }
    __builtin_amdgcn_s_setprio(0);
    __syncthreads();
    cur ^= 1;
  }

  float bv[4];
#pragma unroll
  for (int n = 0; n < 4; ++n) bv[n] = bias[col0 + wn * 64 + n * 16 + fr];
#pragma unroll
  for (int m = 0; m < 4; ++m) {
#pragma unroll
    for (int j = 0; j < 4; ++j) {
      const long row = row0 + wm * 64 + m * 16 + g * 4 + j;
      const long base = row * N + col0 + wn * 64 + fr;
#pragma unroll
      for (int n = 0; n < 4; ++n) {
        float v = acc[m][n][j] + bv[n];
        if constexpr (EPI == 0) {
          ((u16*)outp)[base + n * 16] = f2bf(v);
        } else if constexpr (EPI == 1) {
          ((u16*)outp)[base + n * 16] = f2bf(gelu_f(v));
        } else {
          ((float*)outp)[base + n * 16] = v + res[base + n * 16];
        }
      }
    }
  }
}

template<int EPI>
__global__ __launch_bounds__(256, 4) void gemm9(
    const u16* __restrict__ A, const u16* __restrict__ W,
    const float* __restrict__ bias, const float* __restrict__ res,
    void* __restrict__ outp, int M, int N, int K)
{
  int flat = blockIdx.y * gridDim.x + blockIdx.x;
  const int nwg = gridDim.x * gridDim.y;
  if ((nwg & 7) == 0) flat = (flat & 7) * (nwg >> 3) + (flat >> 3);
  const int bx = flat % gridDim.x;
  const int by = flat / gridDim.x;
  gemm9_core<EPI>(A, W, bias, res, outp, (long)by * 128, (long)bx * 128, N, K);
}

template<int EPI>
__global__ __launch_bounds__(256, 4) void gemm9f(
    const u16* __restrict__ A0, const u16* __restrict__ W0,
    const float* __restrict__ bias0, const float* __restrict__ res0, void* __restrict__ out0,
    const u16* __restrict__ A1, const u16* __restrict__ W1,
    const float* __restrict__ bias1, const float* __restrict__ res1, void* __restrict__ out1,
    int Y0, int N, int K)
{
  int flat = blockIdx.y * gridDim.x + blockIdx.x;
  const int nwg = gridDim.x * gridDim.y;
  if ((nwg & 7) == 0) flat = (flat & 7) * (nwg >> 3) + (flat >> 3);
  const int bx = flat % gridDim.x;
  const int by = flat / gridDim.x;
  if (by < Y0) {
    gemm9_core<EPI>(A0, W0, bias0, res0, out0, (long)by * 128, (long)bx * 128, N, K);
  } else {
    gemm9_core<EPI>(A1, W1, bias1, res1, out1, (long)(by - Y0) * 128, (long)bx * 128, N, K);
  }
}

// ---------------------------------------------------------------------------
// Relative position index (matches _rel_index in reference)
// ---------------------------------------------------------------------------
template<int LQ>
__device__ __forceinline__ int rel_index(int q, int k) {
  if constexpr (LQ == 64) {
    const int qh = q >> 3, qw = q & 7, kh = k >> 4, kw = k & 15;
    return (qh - kh + 15) * 23 + (qw - kw + 15);
  } else {
    const int qh = q >> 4, qw = q & 15, kh = k >> 3, kw = k & 7;
    return (qh - kh + 7) * 23 + (qw - kw + 7);
  }
}

// ---------------------------------------------------------------------------
// Fused cross attention core (16x16 MFMA), dynamic shared, Ps aliased:
//  ALIAS=0: Ps overlays Qs (per-wave self-alias, x-path).
//  ALIAS=1: Ps overlays Ks (z-path; +1 barrier after QK^T).
// ---------------------------------------------------------------------------
template<int LQ, int LK, int ALIAS>
__device__ void attn_core(
    const u16* __restrict__ Q, int qs, const u16* __restrict__ KV, int ks,
    const float* __restrict__ rpb, u16* __restrict__ O, char* sm, int h, int b)
{
  constexpr int MT = LQ / 64;
  constexpr int NT = LK / 16;
  constexpr int KSPV = LK / 32;
  static_assert(LQ * LK == (ALIAS == 0 ? LQ * 64 : LK * 64), "alias size");

  u16* Qs = (u16*)sm;                      // LQ*64
  u16* Ks = Qs + LQ * 64;                  // LK*64
  u16* Vt = Ks + LK * 64;                  // 64*LK
  float* bias_s = (float*)(Vt + 64 * LK);  // 529
  u16* Ps = (ALIAS == 0) ? Qs : Ks;        // LQ*LK (aliased)

  const int tid = threadIdx.x;
  const int lane = tid & 63;
  const int w = tid >> 6;

  for (int i = tid; i < 529; i += 256) bias_s[i] = rpb[i * 12 + h];

#pragma unroll
  for (int it = 0; it < LQ * 8 / 256; ++it) {
    const int s = it * 256 + tid;
    const int r = s >> 3, sl2 = s & 7;
    bf16x8 v = *(const bf16x8*)&Q[(size_t)(b * LQ + r) * qs + h * 64 + sl2 * 8];
    *(bf16x8*)&Qs[r * 64 + ((sl2 ^ (r & 7)) * 8)] = v;
  }
#pragma unroll
  for (int it = 0; it < LK * 8 / 256; ++it) {
    const int s = it * 256 + tid;
    const int r = s >> 3, sl2 = s & 7;
    bf16x8 v = *(const bf16x8*)&KV[(size_t)(b * LK + r) * ks + h * 64 + sl2 * 8];
    *(bf16x8*)&Ks[r * 64 + ((sl2 ^ (r & 7)) * 8)] = v;
  }
#pragma unroll
  for (int it = 0; it < LK * 8 / 256; ++it) {
    const int s = it * 256 + tid;
    const int r = s >> 3, sl2 = s & 7;
    const int d0 = sl2 * 8;
    bf16x8 v = *(const bf16x8*)&KV[(size_t)(b * LK + r) * ks + 768 + h * 64 + d0];
#pragma unroll
    for (int j = 0; j < 8; ++j) {
      const int d = d0 + j;
      Vt[d * LK + (((r >> 3) ^ (d & 7)) * 8) + (r & 7)] = (u16)v[j];
    }
  }
  __syncthreads();

  const int fr = lane & 15;
  const int g = lane >> 4;
  const int qbase = w * MT * 16;

  f32x4 sacc[MT][NT];
#pragma unroll
  for (int mt = 0; mt < MT; ++mt)
#pragma unroll
    for (int nt = 0; nt < NT; ++nt) sacc[mt][nt] = (f32x4){0.f, 0.f, 0.f, 0.f};

#pragma unroll
  for (int mt = 0; mt < MT; ++mt) {
    const int qr = qbase + mt * 16 + fr;
    bf16x8 aq0 = *(const bf16x8*)&Qs[qr * 64 + (((0 + g) ^ (qr & 7)) * 8)];
    bf16x8 aq1 = *(const bf16x8*)&Qs[qr * 64 + (((4 + g) ^ (qr & 7)) * 8)];
#pragma unroll
    for (int nt = 0; nt < NT; ++nt) {
      const int kr = nt * 16 + fr;
      bf16x8 bk0 = *(const bf16x8*)&Ks[kr * 64 + (((0 + g) ^ (kr & 7)) * 8)];
      bf16x8 bk1 = *(const bf16x8*)&Ks[kr * 64 + (((4 + g) ^ (kr & 7)) * 8)];
      sacc[mt][nt] = __builtin_amdgcn_mfma_f32_16x16x32_bf16(aq0, bk0, sacc[mt][nt], 0, 0, 0);
      sacc[mt][nt] = __builtin_amdgcn_mfma_f32_16x16x32_bf16(aq1, bk1, sacc[mt][nt], 0, 0, 0);
    }
  }

  if (ALIAS == 1) __syncthreads();   // all Ks reads done before Ps overwrites

#pragma unroll
  for (int mt = 0; mt < MT; ++mt) {
#pragma unroll
    for (int reg = 0; reg < 4; ++reg) {
      const int q = qbase + mt * 16 + g * 4 + reg;
      float mx = -3.0e38f;
#pragma unroll
      for (int nt = 0; nt < NT; ++nt) {
        const int k = nt * 16 + fr;
        float s = sacc[mt][nt][reg] * 0.125f + bias_s[rel_index<LQ>(q, k)];
        sacc[mt][nt][reg] = s;
        mx = fmaxf(mx, s);
      }
      mx = fmaxf(mx, __shfl_xor(mx, 1));
      mx = fmaxf(mx, __shfl_xor(mx, 2));
      mx = fmaxf(mx, __shfl_xor(mx, 4));
      mx = fmaxf(mx, __shfl_xor(mx, 8));
      float sum = 0.f;
#pragma unroll
      for (int nt = 0; nt < NT; ++nt) {
        float p = __expf(sacc[mt][nt][reg] - mx);
        sacc[mt][nt][reg] = p;
        sum += p;
      }
      sum += __shfl_xor(sum, 1);
      sum += __shfl_xor(sum, 2);
      sum += __shfl_xor(sum, 4);
      sum += __shfl_xor(sum, 8);
      const float inv = 1.0f / sum;
#pragma unroll
      for (int nt = 0; nt < NT; ++nt) {
        const int k = nt * 16 + fr;
        Ps[q * LK + (((k >> 3) ^ (q & 7)) * 8) + (k & 7)] = f2bf(sacc[mt][nt][reg] * inv);
      }
    }
  }
  __syncthreads();

  f32x4 oacc[MT][4];
#pragma unroll
  for (int mt = 0; mt < MT; ++mt)
#pragma unroll
    for (int n = 0; n < 4; ++n) oacc[mt][n] = (f32x4){0.f, 0.f, 0.f, 0.f};

#pragma unroll
  for (int mt = 0; mt < MT; ++mt) {
    const int pr = qbase + mt * 16 + fr;
#pragma unroll
    for (int ks2 = 0; ks2 < KSPV; ++ks2) {
      bf16x8 ap = *(const bf16x8*)&Ps[pr * LK + (((ks2 * 4 + g) ^ (pr & 7)) * 8)];
#pragma unroll
      for (int n = 0; n < 4; ++n) {
        const int d = n * 16 + fr;
        bf16x8 bvv = *(const bf16x8*)&Vt[d * LK + (((ks2 * 4 + g) ^ (d & 7)) * 8)];
        oacc[mt][n] = __builtin_amdgcn_mfma_f32_16x16x32_bf16(ap, bvv, oacc[mt][n], 0, 0, 0);
      }
    }
  }

#pragma unroll
  for (int mt = 0; mt < MT; ++mt)
#pragma unroll
    for (int n = 0; n < 4; ++n)
#pragma unroll
      for (int reg = 0; reg < 4; ++reg) {
        const int q = qbase + mt * 16 + g * 4 + reg;
        const int d = n * 16 + fr;
        O[(size_t)(b * LQ + q) * 768 + h * 64 + d] = f2bf(oacc[mt][n][reg]);
      }
}

template<int LQ, int LK, int ALIAS>
__global__ __launch_bounds__(256) void attn_one(
    const u16* __restrict__ Q, int qs, const u16* __restrict__ KV, int ks,
    const float* __restrict__ rpb, u16* __restrict__ O)
{
  extern __shared__ __align__(16) char smdyn[];
  attn_core<LQ, LK, ALIAS>(Q, qs, KV, ks, rpb, O, smdyn, blockIdx.x, blockIdx.y);
}

// ---------------------------------------------------------------------------
// Host launcher
// ---------------------------------------------------------------------------
extern "C" void kernel_launch(void* const* d_in, const int* in_sizes, int n_in,
                              void* d_out, int out_size, void* d_ws, size_t ws_size,
                              hipStream_t stream)
{
  const float* z      = (const float*)d_in[0];
  const float* x      = (const float*)d_in[1];
  const float* zln1g  = (const float*)d_in[2];
  const float* zln1b  = (const float*)d_in[3];
  const float* xln1g  = (const float*)d_in[4];
  const float* xln1b  = (const float*)d_in[5];
  const float* zx_qw  = (const float*)d_in[6];
  const float* zx_qb  = (const float*)d_in[7];
  const float* zx_kvw = (const float*)d_in[8];
  const float* zx_kvb = (const float*)d_in[9];
  const float* zx_pw  = (const float*)d_in[10];
  const float* zx_pb  = (const float*)d_in[11];
  const float* zx_rpb = (const float*)d_in[12];
  const float* xz_qw  = (const float*)d_in[13];
  const float* xz_qb  = (const float*)d_in[14];
  const float* xz_kvw = (const float*)d_in[15];
  const float* xz_kvb = (const float*)d_in[16];
  const float* xz_pw  = (const float*)d_in[17];
  const float* xz_pb  = (const float*)d_in[18];
  const float* xz_rpb = (const float*)d_in[19];
  const float* zln2g  = (const float*)d_in[20];
  const float* zln2b  = (const float*)d_in[21];
  const float* zfc1w  = (const float*)d_in[22];
  const float* zfc1b  = (const float*)d_in[23];
  const float* zfc2w  = (const float*)d_in[24];
  const float* zfc2b  = (const float*)d_in[25];
  const float* xln2g  = (const float*)d_in[26];
  const float* xln2b  = (const float*)d_in[27];
  const float* xfc1w  = (const float*)d_in[28];
  const float* xfc1b  = (const float*)d_in[29];
  const float* xfc2w  = (const float*)d_in[30];
  const float* xfc2b  = (const float*)d_in[31];

  float* out = (float*)d_out;
  float* z2 = out;                       // 4096 x 768 f32
  float* x2 = out + 3145728;             // 16384 x 768 f32

  char* ws = (char*)d_ws;
  size_t off = 0;
  auto take = [&](size_t bytes) {
    char* p = ws + off;
    off += (bytes + 255) & ~(size_t)255;
    return p;
  };
  u16* w_zn   = (u16*)take(1769472 * 2);   // [zx_qw ; xz_kvw]  (2304 x 768)
  u16* w_xn   = (u16*)take(1769472 * 2);   // [xz_qw ; zx_kvw]
  u16* w_zx_p = (u16*)take(589824 * 2);
  u16* w_xz_p = (u16*)take(589824 * 2);
  u16* w_zfc1 = (u16*)take(2359296 * 2);
  u16* w_zfc2 = (u16*)take(2359296 * 2);
  u16* w_xfc1 = (u16*)take(2359296 * 2);
  u16* w_xfc2 = (u16*)take(2359296 * 2);
  float* b_zn = (float*)take(2304 * 4);
  float* b_xn = (float*)take(2304 * 4);
  u16* regA   = (u16*)take(31457280);      // zn|xn -> ao_z|ao_x -> z2n|x2n

  const size_t need_full = off + 125829120;
  const bool full = (ws_size >= need_full);
  u16* regB = (u16*)take(full ? 125829120 : 94371840);

  u16* zn    = regA;
  u16* xn    = regA + 3145728;
  u16* qkv_z = regB;                        // 4096 x 2304
  u16* qkv_x = regB + 9437184;              // 16384 x 2304
  u16* ao_z  = zn;
  u16* ao_x  = xn;
  u16* z2n   = zn;
  u16* x2n   = xn;
  u16* hz    = regB;                        // 4096 x 3072
  u16* hx    = regB + 12582912;             // 16384 (or 8192) x 3072

  // 1. prep: weight convert + LN1 + bias pack
  PrepArgs a;
  a.csrc[0] = zx_qw;  a.cdst[0] = w_zn;           a.cn[0] = 589824;
  a.csrc[1] = xz_kvw; a.cdst[1] = w_zn + 589824;  a.cn[1] = 1179648;
  a.csrc[2] = xz_qw;  a.cdst[2] = w_xn;           a.cn[2] = 589824;
  a.csrc[3] = zx_kvw; a.cdst[3] = w_xn + 589824;  a.cn[3] = 1179648;
  a.csrc[4] = zx_pw;  a.cdst[4] = w_zx_p;         a.cn[4] = 589824;
  a.csrc[5] = xz_pw;  a.cdst[5] = w_xz_p;         a.cn[5] = 589824;
  a.csrc[6] = zfc1w;  a.cdst[6] = w_zfc1;         a.cn[6] = 2359296;
  a.csrc[7] = zfc2w;  a.cdst[7] = w_zfc2;         a.cn[7] = 2359296;
  a.csrc[8] = xfc1w;  a.cdst[8] = w_xfc1;         a.cn[8] = 2359296;
  a.csrc[9] = xfc2w;  a.cdst[9] = w_xfc2;         a.cn[9] = 2359296;
  a.z = z; a.zg = zln1g; a.zb = zln1b; a.zo = zn;
  a.x = x; a.xg = xln1g; a.xb = xln1b; a.xo = xn;
  a.zq = zx_qb; a.zkv = xz_kvb; a.xq = xz_qb; a.xkv = zx_kvb;
  a.bz = b_zn; a.bx = b_xn;
  prep<<<28169, 256, 0, stream>>>(a);

  // 2. fused packed QKV (gemm6f): zn -> [q_z|kv_z], xn -> [q_x|kv_x]
  gemm6f<0><<<dim3(18, 80), 512, 0, stream>>>(
      zn, w_zn, b_zn, nullptr, qkv_z,
      xn, w_xn, b_xn, nullptr, qkv_x, 16, 2304, 768);

  // 3. attention, dynamic-LDS sized per path (z: 75.8 KB -> 2/CU, x: 51.3 KB -> 3/CU)
  constexpr u32 SZ_Z = (64 * 64 + 256 * 64 + 64 * 256) * 2 + 529 * 4;   // 75844
  constexpr u32 SZ_X = (256 * 64 + 64 * 64 + 64 * 64) * 2 + 529 * 4;    // 51268
  attn_one<64, 256, 1><<<dim3(12, 64), 256, SZ_Z, stream>>>(qkv_z, 2304, qkv_x + 768, 2304, zx_rpb, ao_z);
  attn_one<256, 64, 0><<<dim3(12, 64), 256, SZ_X, stream>>>(qkv_x, 2304, qkv_z + 768, 2304, xz_rpb, ao_x);

  // 4. fused output proj + residual (gemm6f)
  gemm6f<2><<<dim3(6, 80), 512, 0, stream>>>(
      ao_z, w_zx_p, zx_pb, z, z2,
      ao_x, w_xz_p, xz_pb, x, x2, 16, 768, 768);

  // 5. LN2
  ln_dual<<<5120, 256, 0, stream>>>(z2, zln2g, zln2b, z2n, 4096, x2, xln2g, xln2b, x2n);

  // 6. fused MLPs — gemm9 (128-tile, 4 blocks/CU = 16 waves/CU)
  if (full) {
    gemm9f<1><<<dim3(24, 160), 256, 0, stream>>>(
        z2n, w_zfc1, zfc1b, nullptr, hz,
        x2n, w_xfc1, xfc1b, nullptr, hx, 32, 3072, 768);
    gemm9f<2><<<dim3(6, 160), 256, 0, stream>>>(
        hz, w_zfc2, zfc2b, z2, z2,
        hx, w_xfc2, xfc2b, x2, x2, 32, 768, 3072);
  } else {
    gemm9f<1><<<dim3(24, 96), 256, 0, stream>>>(
        z2n, w_zfc1, zfc1b, nullptr, hz,
        x2n, w_xfc1, xfc1b, nullptr, hx, 32, 3072, 768);
    gemm9f<2><<<dim3(6, 96), 256, 0, stream>>>(
        hz, w_zfc2, zfc2b, z2, z2,
        hx, w_xfc2, xfc2b, x2, x2, 32, 768, 3072);
    gemm9<1><<<dim3(24, 64), 256, 0, stream>>>(x2n + (size_t)8192 * 768, w_xfc1, xfc1b, nullptr, hx, 8192, 3072, 768);
    gemm9<2><<<dim3(6, 64), 256, 0, stream>>>(hx, w_xfc2, xfc2b, x2 + (size_t)8192 * 768, x2 + (size_t)8192 * 768, 8192, 768, 3072);
  }
}